// Round 4
// baseline (166.091 us; speedup 1.0000x reference)
//
#include <hip/hip_runtime.h>
#include <hip/hip_bf16.h>
#include <stdint.h>

typedef __attribute__((ext_vector_type(4))) float f32x4;
typedef __attribute__((ext_vector_type(8))) __bf16 bf16x8;
typedef __attribute__((ext_vector_type(4))) __bf16 bf16x4;

#define DEVI __device__ __forceinline__

static constexpr int S_  = 2048;
static constexpr int D_  = 1024;
static constexpr int H_  = 16;
static constexpr int HD_ = 64;
static constexpr int M_  = 2 * S_;   // B*S = 4096 token rows
static constexpr float SCL2 = 0.18033688f;  // 0.125 * log2(e)

DEVI void gload_lds16(const void* gsrc, void* ldst) {
  __builtin_amdgcn_global_load_lds(
      (__attribute__((address_space(1))) void*)(void*)gsrc,
      (__attribute__((address_space(3))) void*)ldst, 16, 0, 0);
}

DEVI float fexp2(float x) {
  float r;
  asm("v_exp_f32 %0, %1" : "=v"(r) : "v"(x));
  return r;
}

__global__ __launch_bounds__(256) void cvt_bf16_kernel(
    const float* __restrict__ in, __bf16* __restrict__ out, int n4) {
  int i = blockIdx.x * 256 + threadIdx.x;
  if (i >= n4) return;
  float4 v = reinterpret_cast<const float4*>(in)[i];
  bf16x4 o;
  o[0] = (__bf16)v.x; o[1] = (__bf16)v.y; o[2] = (__bf16)v.z; o[3] = (__bf16)v.w;
  reinterpret_cast<bf16x4*>(out)[i] = o;
}

// tab[s*32+f] = {cos, sin}(s * 10000^(-2f/64))
__global__ __launch_bounds__(256) void rope_table_kernel(float* __restrict__ tab) {
  int i = blockIdx.x * 256 + threadIdx.x;   // S*32 threads
  int s = i >> 5, f = i & 31;
  float freq = powf(10000.0f, -(float)(2 * f) / (float)HD_);
  float ang = (float)s * freq;
  tab[2 * i]     = cosf(ang);
  tab[2 * i + 1] = sinf(ang);
}

// ---------------------------------------------------------------------------
// QKV GEMM, 256x256 tile, BK=64, 8 waves, 8-phase counted-vmcnt schedule.
// C[m][n] = sum_k A[m][k] * W[n][k]; fused N=3072 (z = weight select).
// LDS: subtiled [rb][kb] 16x32 bf16 subtiles (1024B), st_16x32 swizzle
// (lb ^= ((lb>>9)&1)<<5) realized via pre-swizzled global source (linear
// global_load_lds dest) + swizzled ds_read address.
// Staging stream: half-tile s (tile s>>2, kind s&3: A-k0,B-k0,A-k1,B-k1),
// staged 6 halves ahead, one per phase; vmcnt(4) at each tile's last phase
// (vmcnt(0) at the NT-2 boundary). Raw barriers; setprio around MFMA.
// ---------------------------------------------------------------------------
__global__ __launch_bounds__(512, 2) void gemm_qkv8(
    const __bf16* __restrict__ A, const __bf16* __restrict__ W0,
    const __bf16* __restrict__ W1, const __bf16* __restrict__ W2,
    __bf16* __restrict__ Cq, __bf16* __restrict__ Ck, __bf16* __restrict__ Cv,
    const float* __restrict__ tab) {
  __shared__ __attribute__((aligned(16))) char As[65536];
  __shared__ __attribute__((aligned(16))) char Bs[65536];
  constexpr int NT = 16;                       // K=1024 / BK=64
  const int tid = threadIdx.x, lane = tid & 63, wv = tid >> 6;
  const int wr = wv >> 2, wc = wv & 3;         // wave 2M x 4N

  // XCD-contiguous block swizzle (192 blocks, 192%8==0 -> bijective)
  int bid = blockIdx.y * 16 + blockIdx.x;
  int swb = (bid & 7) * 24 + (bid >> 3);
  const int bx = swb & 15, by = swb >> 4;
  const int m0 = bx * 256;
  const int z = by >> 2;
  const int nloc0 = (by & 3) * 256;
  const __bf16* W = (z == 0) ? W0 : (z == 1 ? W1 : W2);
  const __bf16* Ab = A + (size_t)m0 * 1024;
  const __bf16* Wb = W + (size_t)nloc0 * 1024;

  // staging: lane -> source element within subtile (inverse swizzle)
  const int sr  = lane >> 2;                               // row in subtile
  const int scq = ((lane & 3) * 8) ^ ((lane >> 5) << 4);   // col in subtile

#define STAGE_HALF(S)                                                        \
  do {                                                                       \
    int s_ = (S);                                                            \
    if (s_ < 4 * NT) {                                                       \
      int ts_ = s_ >> 2, kind_ = s_ & 3;                                     \
      int kb_ = kind_ >> 1;                                                  \
      const __bf16* gb_ = (kind_ & 1) ? Wb : Ab;                             \
      char* lb_ = ((kind_ & 1) ? Bs : As) + (ts_ & 1) * 32768 + kb_ * 1024;  \
      int kg_ = ts_ * 64 + kb_ * 32 + scq;                                   \
      _Pragma("unroll") for (int jj = 0; jj < 2; ++jj) {                     \
        int rb_ = jj * 8 + wv;                                               \
        gload_lds16(gb_ + (size_t)(rb_ * 16 + sr) * 1024 + kg_,              \
                    lb_ + rb_ * 2048);                                       \
      }                                                                      \
    }                                                                        \
  } while (0)

  f32x4 acc[8][4];
#pragma unroll
  for (int i = 0; i < 8; i++)
#pragma unroll
    for (int j = 0; j < 4; j++) acc[i][j] = f32x4{0.f, 0.f, 0.f, 0.f};

  // swizzled ds_read byte offset within a subtile
  int lbr = ((lane & 15) << 6) | ((lane >> 4) << 4);
  lbr ^= ((lane >> 3) & 1) << 5;

  // prologue: prime stream s=0..5; tile0 landed, s=4,5 in flight
  STAGE_HALF(0); STAGE_HALF(1); STAGE_HALF(2);
  STAGE_HALF(3); STAGE_HALF(4); STAGE_HALF(5);
  asm volatile("s_waitcnt vmcnt(4)" ::: "memory");
  __builtin_amdgcn_s_barrier();
  __builtin_amdgcn_sched_barrier(0);

#define PHASE(MH, KS, PH, LASTP)                                             \
  do {                                                                       \
    const char* Ab_ = As + cur * 32768 + (KS) * 1024 + lbr;                  \
    const char* Bb_ = Bs + cur * 32768 + (KS) * 1024 + lbr;                  \
    if ((MH) == 0) {                                                         \
      _Pragma("unroll") for (int j = 0; j < 4; ++j)                          \
        bfr[j] = *reinterpret_cast<const bf16x8*>(Bb_ + (wc * 4 + j) * 2048);\
    }                                                                        \
    bf16x8 afr[4];                                                           \
    _Pragma("unroll") for (int i = 0; i < 4; ++i)                            \
      afr[i] = *reinterpret_cast<const bf16x8*>(                             \
          Ab_ + (wr * 8 + (MH) * 4 + i) * 2048);                             \
    STAGE_HALF(u * 4 + (PH) + 6);                                            \
    __builtin_amdgcn_sched_barrier(0);                                       \
    __builtin_amdgcn_s_barrier();                                            \
    __builtin_amdgcn_sched_barrier(0);                                       \
    __builtin_amdgcn_s_setprio(1);                                           \
    _Pragma("unroll") for (int i = 0; i < 4; ++i)                            \
      _Pragma("unroll") for (int j = 0; j < 4; ++j)                          \
        acc[(MH) * 4 + i][j] = __builtin_amdgcn_mfma_f32_16x16x32_bf16(      \
            afr[i], bfr[j], acc[(MH) * 4 + i][j], 0, 0, 0);                  \
    __builtin_amdgcn_s_setprio(0);                                           \
    __builtin_amdgcn_sched_barrier(0);                                       \
    if (LASTP) {                                                             \
      if (u < NT - 2)                                                        \
        asm volatile("s_waitcnt vmcnt(4)" ::: "memory");                     \
      else if (u == NT - 2)                                                  \
        asm volatile("s_waitcnt vmcnt(0)" ::: "memory");                     \
    }                                                                        \
    __builtin_amdgcn_s_barrier();                                            \
    __builtin_amdgcn_sched_barrier(0);                                       \
  } while (0)

  for (int u = 0; u < NT; ++u) {
    const int cur = u & 1;
    bf16x8 bfr[4];
    PHASE(0, 0, 0, false);
    PHASE(1, 0, 1, false);
    PHASE(0, 1, 2, false);
    PHASE(1, 1, 3, true);
  }
#undef PHASE
#undef STAGE_HALF

  // epilogue: RoPE + head-split. C/D: col=lane&15 (n), row=(lane>>4)*4+rr (m)
#pragma unroll
  for (int fi = 0; fi < 8; ++fi) {
#pragma unroll
    for (int fj = 0; fj < 4; ++fj) {
#pragma unroll
      for (int rr = 0; rr < 4; ++rr) {
        int m  = m0 + wr * 128 + fi * 16 + (lane >> 4) * 4 + rr;
        int nw = nloc0 + wc * 64 + fj * 16 + (lane & 15);
        float v = acc[fi][fj][rr];
        int bb = m >> 11, srow = m & (S_ - 1);
        int h = nw >> 6, d = nw & 63;
        size_t oidx = ((size_t)(bb * H_ + h) * S_ + srow) * HD_ + d;
        float other = __shfl_xor(v, 1, 64);   // n bit0 == lane bit0
        if (z == 2) {
          Cv[oidx] = (__bf16)v;
        } else {
          int fq = d >> 1;
          float cs = tab[(srow * 32 + fq) * 2];
          float sn = tab[(srow * 32 + fq) * 2 + 1];
          float rv = (d & 1) ? (other * sn + v * cs) : (v * cs - other * sn);
          if (z == 0) rv *= SCL2;   // pre-scale Q: logits in exp2 domain
          ((z == 0) ? Cq : Ck)[oidx] = (__bf16)rv;
        }
      }
    }
  }
}

// O-projection: C[m][n] = sum_k A[m][k] * W[n][k], fp32 out (m97 structure)
__global__ __launch_bounds__(256) void gemm_bt0(
    const __bf16* __restrict__ A, const __bf16* __restrict__ W0,
    float* __restrict__ Cf, int M, int N, int K) {
  constexpr int BM = 128, BN = 128, BK = 32;
  __shared__ __attribute__((aligned(16))) __bf16 As[BM * BK];
  __shared__ __attribute__((aligned(16))) __bf16 Bs[BN * BK];
  const int tid  = threadIdx.x;
  const int lane = tid & 63;
  const int wv   = tid >> 6;
  const int m0 = blockIdx.x * BM;
  const int n0 = blockIdx.y * BN;
  const int wm = (wv >> 1) * 64, wn = (wv & 1) * 64;
  const int arow = lane & 15;
  const int kgrp = (lane >> 4) * 8;

  f32x4 acc[4][4];
#pragma unroll
  for (int i = 0; i < 4; i++)
#pragma unroll
    for (int j = 0; j < 4; j++) acc[i][j] = f32x4{0.f, 0.f, 0.f, 0.f};

  for (int k0 = 0; k0 < K; k0 += BK) {
    __syncthreads();
#pragma unroll
    for (int j = 0; j < 2; ++j) {
      int c   = (wv * 2 + j) * 64 + lane;
      int row = c >> 2;
      int kc  = (c & 3) * 8;
      gload_lds16(A + (size_t)(m0 + row) * K + k0 + kc,
                  As + (size_t)(wv * 2 + j) * 512);
      gload_lds16(W0 + (size_t)(n0 + row) * K + k0 + kc,
                  Bs + (size_t)(wv * 2 + j) * 512);
    }
    asm volatile("s_waitcnt vmcnt(0)" ::: "memory");
    __syncthreads();
    bf16x8 af[4], bw[4];
#pragma unroll
    for (int i = 0; i < 4; i++)
      af[i] = *reinterpret_cast<const bf16x8*>(As + (wm + i * 16 + arow) * BK + kgrp);
#pragma unroll
    for (int i = 0; i < 4; i++)
      bw[i] = *reinterpret_cast<const bf16x8*>(Bs + (wn + i * 16 + arow) * BK + kgrp);
#pragma unroll
    for (int i = 0; i < 4; i++)
#pragma unroll
      for (int j = 0; j < 4; j++)
        acc[i][j] = __builtin_amdgcn_mfma_f32_16x16x32_bf16(af[i], bw[j], acc[i][j], 0, 0, 0);
  }

#pragma unroll
  for (int i = 0; i < 4; i++)
#pragma unroll
    for (int j = 0; j < 4; j++)
#pragma unroll
      for (int r = 0; r < 4; r++) {
        int m = m0 + wm + i * 16 + (lane >> 4) * 4 + r;
        int n = n0 + wn + j * 16 + arow;
        Cf[(size_t)m * N + n] = acc[i][j][r];
      }
}

// V [bh][s][d=64] -> Vt [bh][d][s].  Tile 64s x 64d per block.
__global__ __launch_bounds__(256) void vtrans_kernel(
    const __bf16* __restrict__ V, __bf16* __restrict__ Vt) {
  __shared__ __attribute__((aligned(16))) char T[64 * 144]; // row d, 144B stride
  const int bh = blockIdx.y, s0 = blockIdx.x * 64;
  const __bf16* Vb = V + (size_t)bh * S_ * HD_;
  __bf16* Vtb = Vt + (size_t)bh * HD_ * S_;
  const int tid = threadIdx.x;
#pragma unroll
  for (int j = 0; j < 2; ++j) {
    int c = tid + j * 256;            // s = c>>3, dc = c&7
    int s = c >> 3, dc = c & 7;
    bf16x8 v = *reinterpret_cast<const bf16x8*>(Vb + (size_t)(s0 + s) * HD_ + dc * 8);
#pragma unroll
    for (int e = 0; e < 8; ++e) {
      int d = dc * 8 + e;
      int byt = (d * 144 + s * 2) ^ ((dc & 7) << 4);   // spread banks by dc
      *reinterpret_cast<__bf16*>(T + byt) = v[e];
    }
  }
  __syncthreads();
#pragma unroll
  for (int j = 0; j < 2; ++j) {
    int c = tid + j * 256;            // d = c>>3, sc = c&7
    int d = c >> 3, sc = c & 7;
    int byt = (d * 144 + sc * 16) ^ (((d >> 3) & 7) << 4);
    bf16x8 o = *reinterpret_cast<const bf16x8*>(T + byt);
    *reinterpret_cast<bf16x8*>(Vtb + (size_t)d * S_ + s0 + sc * 8) = o;
  }
}

// Flash attention, causal. Grid: (bh=32, pr=16). Block: 4 waves x 16 q-rows,
// paired q-tiles (pr, 31-pr) => uniform 33 kv-iters per block.
// Swapped QK^T: sc = mfma(K_frag, Q_frag) -> D[key][q], q = lane&15.
// K staged with key-permutation kph so each lane's 16 P-values are exactly
// the PV B-fragment (k = (lane>>4)*8+i) -> softmax + P fully in registers.
__global__ __launch_bounds__(256) void attn_kernel(
    const __bf16* __restrict__ Q, const __bf16* __restrict__ K,
    const __bf16* __restrict__ Vt, __bf16* __restrict__ O) {
  __shared__ __attribute__((aligned(16))) __bf16 Ks[2][64 * 64];
  __shared__ __attribute__((aligned(16))) __bf16 Vs[2][64 * 64];
  const int tid = threadIdx.x, lane = tid & 63, wv = tid >> 6;
  const int bh = blockIdx.x;
  const int pr = blockIdx.y;
  const int b = bh >> 4, h = bh & 15;
  const __bf16* Qb  = Q  + (size_t)bh * S_ * HD_;
  const __bf16* Kb  = K  + (size_t)bh * S_ * HD_;
  const __bf16* Vtb = Vt + (size_t)bh * HD_ * S_;
  const int arow = lane & 15, g = lane >> 4;

#define STAGE(K0, BK_, BV_)                                                   \
  do {                                                                        \
    _Pragma("unroll") for (int j = 0; j < 2; ++j) {                           \
      int G = (wv * 2 + j) * 64 + lane;                                       \
      int row = G >> 3, qq = G & 7;                                           \
      int qs = qq ^ (row & 7);                                                \
      int ctp = row >> 4, rw = row & 15;                                      \
      int kph = ((ctp >> 1) << 5) + ((rw >> 2) << 3) + ((ctp & 1) << 2)       \
                + (rw & 3);                                                   \
      gload_lds16(Kb + (size_t)((K0) + kph) * HD_ + qs * 8,                   \
                  (BK_) + (wv * 2 + j) * 512);                                \
      gload_lds16(Vtb + (size_t)row * S_ + (K0) + qs * 8,                     \
                  (BV_) + (wv * 2 + j) * 512);                                \
    }                                                                         \
  } while (0)

  for (int seg = 0; seg < 2; ++seg) {
    const int qt = (seg == 0) ? pr : 31 - pr;
    const int q0 = qt * 64;
    const int nkv = qt + 1;
    const int qw = q0 + wv * 16;
    const int qg = qw + arow;          // this thread's q-row

    bf16x8 aq[2];
#pragma unroll
    for (int j = 0; j < 2; j++)
      aq[j] = *reinterpret_cast<const bf16x8*>(
          Qb + (size_t)(qw + arow) * HD_ + j * 32 + g * 8);

    f32x4 po[4];
#pragma unroll
    for (int dt = 0; dt < 4; dt++) po[dt] = f32x4{0.f, 0.f, 0.f, 0.f};
    float mrow = -1e30f, lrow = 0.f;

    STAGE(0, Ks[0], Vs[0]);
    asm volatile("s_waitcnt vmcnt(0)" ::: "memory");
    __syncthreads();

    for (int kt = 0; kt < nkv; ++kt) {
      const int k0 = kt * 64;
      const int cur = kt & 1;
      if (kt + 1 < nkv) STAGE(k0 + 64, Ks[cur ^ 1], Vs[cur ^ 1]);
      const __bf16* Kc = Ks[cur];
      const __bf16* Vc = Vs[cur];

      // S^T = K Q^T : D[key][q], 8 MFMA
      f32x4 sc4[4];
      __builtin_amdgcn_s_setprio(1);
#pragma unroll
      for (int ct = 0; ct < 4; ct++) {
        sc4[ct] = f32x4{0.f, 0.f, 0.f, 0.f};
        int L = ct * 16 + arow;
#pragma unroll
        for (int j2 = 0; j2 < 2; j2++) {
          int byt = (L * 128 + j2 * 64 + g * 16) ^ ((L & 7) << 4);
          bf16x8 kb = *reinterpret_cast<const bf16x8*>((const char*)Kc + byt);
          sc4[ct] = __builtin_amdgcn_mfma_f32_16x16x32_bf16(kb, aq[j2], sc4[ct], 0, 0, 0);
        }
      }
      __builtin_amdgcn_s_setprio(0);

      // causal mask (diagonal tile only)
      const bool full = (kt < nkv - 1);
      if (!full) {
#pragma unroll
        for (int ct = 0; ct < 4; ct++) {
          int kb0 = k0 + ((ct >> 1) << 5) + ((ct & 1) << 2) + g * 8;
#pragma unroll
          for (int r = 0; r < 4; r++)
            if (kb0 + r > qg) sc4[ct][r] = -1e30f;
        }
      }

      // in-register online softmax (one q-row per lane)
      float mx = -1e30f;
#pragma unroll
      for (int ct = 0; ct < 4; ct++)
#pragma unroll
        for (int r = 0; r < 4; r++) mx = fmaxf(mx, sc4[ct][r]);
      mx = fmaxf(mx, __shfl_xor(mx, 16, 64));
      mx = fmaxf(mx, __shfl_xor(mx, 32, 64));

      bool noskip = !__all(mx <= mrow + 11.0f);
      if (noskip) {
        float mnew = fmaxf(mrow, mx);
        float corr = fexp2(mrow - mnew);
        mrow = mnew;
        lrow *= corr;
#pragma unroll
        for (int dt = 0; dt < 4; dt++)
#pragma unroll
          for (int r = 0; r < 4; r++) po[dt][r] *= corr;
      }

      float rs = 0.f;
      float pv[4][4];
#pragma unroll
      for (int ct = 0; ct < 4; ct++)
#pragma unroll
        for (int r = 0; r < 4; r++) {
          float e = fexp2(sc4[ct][r] - mrow);
          pv[ct][r] = e;
          rs += e;
        }
      rs += __shfl_xor(rs, 16, 64);
      rs += __shfl_xor(rs, 32, 64);
      lrow += rs;

      // pack P: pb[j2] holds physical keys j2*32 + g*8 .. +7 (lane-local)
      bf16x8 pb[2];
#pragma unroll
      for (int j2 = 0; j2 < 2; j2++) {
#pragma unroll
        for (int r = 0; r < 4; r++) {
          pb[j2][r]     = (__bf16)pv[2 * j2][r];
          pb[j2][4 + r] = (__bf16)pv[2 * j2 + 1][r];
        }
      }

      // O^T += V^T P^T : po[dt] = D[d][q], d = dt*16 + g*4 + r, q = arow
      __builtin_amdgcn_s_setprio(1);
#pragma unroll
      for (int dt = 0; dt < 4; dt++) {
        int d = dt * 16 + arow;
#pragma unroll
        for (int j2 = 0; j2 < 2; j2++) {
          int byv = (d * 128 + j2 * 64 + g * 16) ^ ((d & 7) << 4);
          bf16x8 vb = *reinterpret_cast<const bf16x8*>((const char*)Vc + byv);
          po[dt] = __builtin_amdgcn_mfma_f32_16x16x32_bf16(vb, pb[j2], po[dt], 0, 0, 0);
        }
      }
      __builtin_amdgcn_s_setprio(0);

      asm volatile("s_waitcnt vmcnt(0)" ::: "memory");
      __syncthreads();
    }

    float inv = __builtin_amdgcn_rcpf(lrow);
#pragma unroll
    for (int dt = 0; dt < 4; dt++) {
      bf16x4 o4;
#pragma unroll
      for (int r = 0; r < 4; r++) o4[r] = (__bf16)(po[dt][r] * inv);
      *reinterpret_cast<bf16x4*>(
          O + (size_t)(b * S_ + qg) * D_ + h * HD_ + dt * 16 + g * 4) = o4;
    }
  }
#undef STAGE
}

extern "C" void kernel_launch(void* const* d_in, const int* in_sizes, int n_in,
                              void* d_out, int out_size, void* d_ws, size_t ws_size,
                              hipStream_t stream) {
  const float* x  = (const float*)d_in[0];
  const float* wq = (const float*)d_in[1];
  const float* wk = (const float*)d_in[2];
  const float* wv = (const float*)d_in[3];
  const float* wo = (const float*)d_in[4];
  float* out = (float*)d_out;

  char* w = (char*)d_ws;
  __bf16* xb  = (__bf16*)(w);                    // 8 MB (reused as Vt later)
  __bf16* wqb = (__bf16*)(w + (8u  << 20));      // 2 MB each
  __bf16* wkb = (__bf16*)(w + (10u << 20));
  __bf16* wvb = (__bf16*)(w + (12u << 20));
  __bf16* wob = (__bf16*)(w + (14u << 20));
  __bf16* qws = (__bf16*)(w + (16u << 20));      // 8 MB each, [B][H][S][hd]
  __bf16* kws = (__bf16*)(w + (24u << 20));
  __bf16* vws = (__bf16*)(w + (32u << 20));
  __bf16* aws = (__bf16*)(w + (40u << 20));      // attn out, [token][feature]
  float*  tab = (float*)(w + (48u << 20));       // 512 KB rope table
  __bf16* vtw = xb;                              // Vt overlays xb (dead after QKV)

  cvt_bf16_kernel<<<M_ * D_ / 4 / 256, 256, 0, stream>>>(x,  xb,  M_ * D_ / 4);
  cvt_bf16_kernel<<<D_ * D_ / 4 / 256, 256, 0, stream>>>(wq, wqb, D_ * D_ / 4);
  cvt_bf16_kernel<<<D_ * D_ / 4 / 256, 256, 0, stream>>>(wk, wkb, D_ * D_ / 4);
  cvt_bf16_kernel<<<D_ * D_ / 4 / 256, 256, 0, stream>>>(wv, wvb, D_ * D_ / 4);
  cvt_bf16_kernel<<<D_ * D_ / 4 / 256, 256, 0, stream>>>(wo, wob, D_ * D_ / 4);
  rope_table_kernel<<<(S_ * 32) / 256, 256, 0, stream>>>(tab);

  gemm_qkv8<<<dim3(16, 12), 512, 0, stream>>>(xb, wqb, wkb, wvb,
                                              qws, kws, vws, tab);
  vtrans_kernel<<<dim3(S_ / 64, 2 * H_), 256, 0, stream>>>(vws, vtw);
  attn_kernel<<<dim3(2 * H_, S_ / 128), 256, 0, stream>>>(qws, kws, vtw, aws);
  gemm_bt0<<<dim3(M_ / 128, D_ / 128), 256, 0, stream>>>(aws, wob, out,
                                                         M_, D_, D_);
}

// Round 5
// 158.721 us; speedup vs baseline: 1.0464x; 1.0464x over previous
//
#include <hip/hip_runtime.h>
#include <hip/hip_bf16.h>
#include <stdint.h>

typedef __attribute__((ext_vector_type(4))) float f32x4;
typedef __attribute__((ext_vector_type(8))) __bf16 bf16x8;
typedef __attribute__((ext_vector_type(4))) __bf16 bf16x4;

#define DEVI __device__ __forceinline__

static constexpr int S_  = 2048;
static constexpr int D_  = 1024;
static constexpr int H_  = 16;
static constexpr int HD_ = 64;
static constexpr int M_  = 2 * S_;   // B*S = 4096 token rows
static constexpr float SCL2 = 0.18033688f;  // 0.125 * log2(e)

DEVI void gload_lds16(const void* gsrc, void* ldst) {
  __builtin_amdgcn_global_load_lds(
      (__attribute__((address_space(1))) void*)(void*)gsrc,
      (__attribute__((address_space(3))) void*)ldst, 16, 0, 0);
}

DEVI float fexp2(float x) {
  float r;
  asm("v_exp_f32 %0, %1" : "=v"(r) : "v"(x));
  return r;
}

// One fused conversion kernel: x + 4 weights fp32->bf16, plus RoPE table.
// Blocks [0,8192): cvt (2M float4 total). Blocks [8192,8448): table.
__global__ __launch_bounds__(256) void cvt_all_kernel(
    const float* __restrict__ x, const float* __restrict__ wq,
    const float* __restrict__ wk, const float* __restrict__ wv,
    const float* __restrict__ wo,
    __bf16* __restrict__ xb, __bf16* __restrict__ wqb,
    __bf16* __restrict__ wkb, __bf16* __restrict__ wvb,
    __bf16* __restrict__ wob, float* __restrict__ tab) {
  int blk = blockIdx.x;
  if (blk < 8192) {
    int i = blk * 256 + threadIdx.x;     // float4 index
    const float* src; __bf16* dst; int off;
    if (i < (1 << 20))                      { src = x;  dst = xb;  off = 0; }
    else if (i < (1 << 20) + (1 << 18))     { src = wq; dst = wqb; off = (1 << 20); }
    else if (i < (1 << 20) + 2 * (1 << 18)) { src = wk; dst = wkb; off = (1 << 20) + (1 << 18); }
    else if (i < (1 << 20) + 3 * (1 << 18)) { src = wv; dst = wvb; off = (1 << 20) + 2 * (1 << 18); }
    else                                    { src = wo; dst = wob; off = (1 << 20) + 3 * (1 << 18); }
    int j = i - off;
    float4 v = reinterpret_cast<const float4*>(src)[j];
    bf16x4 o;
    o[0] = (__bf16)v.x; o[1] = (__bf16)v.y; o[2] = (__bf16)v.z; o[3] = (__bf16)v.w;
    reinterpret_cast<bf16x4*>(dst)[j] = o;
  } else {
    int i = (blk - 8192) * 256 + threadIdx.x;   // 0..65535 = S*32
    int s = i >> 5, f = i & 31;
    float freq = powf(10000.0f, -(float)(2 * f) / (float)HD_);
    float ang = (float)s * freq;
    tab[2 * i]     = cosf(ang);
    tab[2 * i + 1] = sinf(ang);
  }
}

// ---------------------------------------------------------------------------
// QKV GEMM, 256x256 tile, BK=64, 8 waves, 4-phase/K-tile counted-vmcnt
// schedule (m201 template). C[m][n] = sum_k A[m][k]*W[n][k]; fused N=3072.
// LDS subtiles 16x32 bf16 (1024B), st_16x32 swizzle via pre-swizzled global
// source (linear global_load_lds dest) + swizzled ds_read.
// Prefetch stream: half s -> tile ts=s>>2, kind q=s&3 in order
// (B-k0, A-k0, B-k1, A-k1); issue s = 4u+PH+7 (3 half-tiles ahead);
// vmcnt(6) once per tile (vmcnt(0) at NT-2). NO sched_barrier (m141).
// Write-after-read audit: q0@ph1 (B-k0 reads end ph0), q1@ph2 (A-k0 ends
// ph1), q2@ph3 (B-k1 ends ph2), q3@next-ph0 (A-k1 ends ph3).
// ---------------------------------------------------------------------------
__global__ __launch_bounds__(512, 2) void gemm_qkv8(
    const __bf16* __restrict__ A, const __bf16* __restrict__ W0,
    const __bf16* __restrict__ W1, const __bf16* __restrict__ W2,
    __bf16* __restrict__ Cq, __bf16* __restrict__ Ck, __bf16* __restrict__ Cv,
    const float* __restrict__ tab) {
  __shared__ __attribute__((aligned(16))) char As[65536];
  __shared__ __attribute__((aligned(16))) char Bs[65536];
  constexpr int NT = 16;                       // K=1024 / BK=64
  const int tid = threadIdx.x, lane = tid & 63, wv = tid >> 6;
  const int wr = wv >> 2, wc = wv & 3;         // wave 2M x 4N

  // XCD-contiguous block swizzle (192 blocks, 192%8==0 -> bijective)
  int bid = blockIdx.y * 16 + blockIdx.x;
  int swb = (bid & 7) * 24 + (bid >> 3);
  const int bx = swb & 15, by = swb >> 4;
  const int m0 = bx * 256;
  const int z = by >> 2;
  const int nloc0 = (by & 3) * 256;
  const __bf16* W = (z == 0) ? W0 : (z == 1 ? W1 : W2);
  const __bf16* Ab = A + (size_t)m0 * 1024;
  const __bf16* Wb = W + (size_t)nloc0 * 1024;

  // staging: lane -> source element within subtile (inverse swizzle)
  const int sr  = lane >> 2;                               // row in subtile
  const int scq = ((lane & 3) * 8) ^ ((lane >> 5) << 4);   // col in subtile

  // stream kind q: 0=B-k0, 1=A-k0, 2=B-k1, 3=A-k1
#define STAGE_HALF(S)                                                        \
  do {                                                                       \
    int s_ = (S);                                                            \
    if (s_ < 4 * NT) {                                                       \
      int ts_ = s_ >> 2, q_ = s_ & 3;                                        \
      int kb_ = q_ >> 1;                                                     \
      const __bf16* gb_ = (q_ & 1) ? Ab : Wb;                                \
      char* lb_ = ((q_ & 1) ? As : Bs) + (ts_ & 1) * 32768 + kb_ * 1024;     \
      int kg_ = ts_ * 64 + kb_ * 32 + scq;                                   \
      _Pragma("unroll") for (int jj = 0; jj < 2; ++jj) {                     \
        int rb_ = jj * 8 + wv;                                               \
        gload_lds16(gb_ + (size_t)(rb_ * 16 + sr) * 1024 + kg_,              \
                    lb_ + rb_ * 2048);                                       \
      }                                                                      \
    }                                                                        \
  } while (0)

  f32x4 acc[8][4];
#pragma unroll
  for (int i = 0; i < 8; i++)
#pragma unroll
    for (int j = 0; j < 4; j++) acc[i][j] = f32x4{0.f, 0.f, 0.f, 0.f};

  // swizzled ds_read byte offset within a subtile
  int lbr = ((lane & 15) << 6) | ((lane >> 4) << 4);
  lbr ^= ((lane >> 3) & 1) << 5;

  // prologue: prime s=0..6; tile0 landed after vmcnt(6)
  STAGE_HALF(0); STAGE_HALF(1); STAGE_HALF(2); STAGE_HALF(3);
  STAGE_HALF(4); STAGE_HALF(5); STAGE_HALF(6);
  asm volatile("s_waitcnt vmcnt(6)" ::: "memory");
  __builtin_amdgcn_s_barrier();

#define PHASE(MH, KS, PH, LASTP)                                             \
  do {                                                                       \
    const char* Ab_ = As + cur * 32768 + (KS) * 1024 + lbr;                  \
    const char* Bb_ = Bs + cur * 32768 + (KS) * 1024 + lbr;                  \
    if ((MH) == 0) {                                                         \
      _Pragma("unroll") for (int j = 0; j < 4; ++j)                          \
        bfr[j] = *reinterpret_cast<const bf16x8*>(Bb_ + (wc * 4 + j) * 2048);\
    }                                                                        \
    bf16x8 afr[4];                                                           \
    _Pragma("unroll") for (int i = 0; i < 4; ++i)                            \
      afr[i] = *reinterpret_cast<const bf16x8*>(                             \
          Ab_ + (wr * 8 + (MH) * 4 + i) * 2048);                             \
    STAGE_HALF(u * 4 + (PH) + 7);                                            \
    __builtin_amdgcn_s_barrier();                                            \
    __builtin_amdgcn_s_setprio(1);                                           \
    _Pragma("unroll") for (int i = 0; i < 4; ++i)                            \
      _Pragma("unroll") for (int j = 0; j < 4; ++j)                          \
        acc[(MH) * 4 + i][j] = __builtin_amdgcn_mfma_f32_16x16x32_bf16(      \
            afr[i], bfr[j], acc[(MH) * 4 + i][j], 0, 0, 0);                  \
    __builtin_amdgcn_s_setprio(0);                                           \
    if (LASTP) {                                                             \
      if (u < NT - 2)                                                        \
        asm volatile("s_waitcnt vmcnt(6)" ::: "memory");                     \
      else if (u == NT - 2)                                                  \
        asm volatile("s_waitcnt vmcnt(0)" ::: "memory");                     \
    }                                                                        \
    __builtin_amdgcn_s_barrier();                                            \
  } while (0)

  for (int u = 0; u < NT; ++u) {
    const int cur = u & 1;
    bf16x8 bfr[4];
    PHASE(0, 0, 0, false);
    PHASE(1, 0, 1, false);
    PHASE(0, 1, 2, false);
    PHASE(1, 1, 3, true);
  }
#undef PHASE
#undef STAGE_HALF

  // epilogue: RoPE + head-split. C/D: col=lane&15 (n), row=(lane>>4)*4+rr (m)
#pragma unroll
  for (int fi = 0; fi < 8; ++fi) {
#pragma unroll
    for (int fj = 0; fj < 4; ++fj) {
#pragma unroll
      for (int rr = 0; rr < 4; ++rr) {
        int m  = m0 + wr * 128 + fi * 16 + (lane >> 4) * 4 + rr;
        int nw = nloc0 + wc * 64 + fj * 16 + (lane & 15);
        float v = acc[fi][fj][rr];
        int bb = m >> 11, srow = m & (S_ - 1);
        int h = nw >> 6, d = nw & 63;
        size_t oidx = ((size_t)(bb * H_ + h) * S_ + srow) * HD_ + d;
        float other = __shfl_xor(v, 1, 64);   // n bit0 == lane bit0
        if (z == 2) {
          Cv[oidx] = (__bf16)v;
        } else {
          int fq = d >> 1;
          float cs = tab[(srow * 32 + fq) * 2];
          float sn = tab[(srow * 32 + fq) * 2 + 1];
          float rv = (d & 1) ? (other * sn + v * cs) : (v * cs - other * sn);
          if (z == 0) rv *= SCL2;   // pre-scale Q: logits in exp2 domain
          ((z == 0) ? Cq : Ck)[oidx] = (__bf16)rv;
        }
      }
    }
  }
}

// O-projection: C[m][n] = sum_k A[m][k] * W[n][k], fp32 out (m97 structure)
__global__ __launch_bounds__(256) void gemm_bt0(
    const __bf16* __restrict__ A, const __bf16* __restrict__ W0,
    float* __restrict__ Cf, int M, int N, int K) {
  constexpr int BM = 128, BN = 128, BK = 32;
  __shared__ __attribute__((aligned(16))) __bf16 As[BM * BK];
  __shared__ __attribute__((aligned(16))) __bf16 Bs[BN * BK];
  const int tid  = threadIdx.x;
  const int lane = tid & 63;
  const int wv   = tid >> 6;
  const int m0 = blockIdx.x * BM;
  const int n0 = blockIdx.y * BN;
  const int wm = (wv >> 1) * 64, wn = (wv & 1) * 64;
  const int arow = lane & 15;
  const int kgrp = (lane >> 4) * 8;

  f32x4 acc[4][4];
#pragma unroll
  for (int i = 0; i < 4; i++)
#pragma unroll
    for (int j = 0; j < 4; j++) acc[i][j] = f32x4{0.f, 0.f, 0.f, 0.f};

  for (int k0 = 0; k0 < K; k0 += BK) {
    __syncthreads();
#pragma unroll
    for (int j = 0; j < 2; ++j) {
      int c   = (wv * 2 + j) * 64 + lane;
      int row = c >> 2;
      int kc  = (c & 3) * 8;
      gload_lds16(A + (size_t)(m0 + row) * K + k0 + kc,
                  As + (size_t)(wv * 2 + j) * 512);
      gload_lds16(W0 + (size_t)(n0 + row) * K + k0 + kc,
                  Bs + (size_t)(wv * 2 + j) * 512);
    }
    asm volatile("s_waitcnt vmcnt(0)" ::: "memory");
    __syncthreads();
    bf16x8 af[4], bw[4];
#pragma unroll
    for (int i = 0; i < 4; i++)
      af[i] = *reinterpret_cast<const bf16x8*>(As + (wm + i * 16 + arow) * BK + kgrp);
#pragma unroll
    for (int i = 0; i < 4; i++)
      bw[i] = *reinterpret_cast<const bf16x8*>(Bs + (wn + i * 16 + arow) * BK + kgrp);
#pragma unroll
    for (int i = 0; i < 4; i++)
#pragma unroll
      for (int j = 0; j < 4; j++)
        acc[i][j] = __builtin_amdgcn_mfma_f32_16x16x32_bf16(af[i], bw[j], acc[i][j], 0, 0, 0);
  }

#pragma unroll
  for (int i = 0; i < 4; i++)
#pragma unroll
    for (int j = 0; j < 4; j++)
#pragma unroll
      for (int r = 0; r < 4; r++) {
        int m = m0 + wm + i * 16 + (lane >> 4) * 4 + r;
        int n = n0 + wn + j * 16 + arow;
        Cf[(size_t)m * N + n] = acc[i][j][r];
      }
}

// V [bh][s][d=64] -> Vt [bh][d][s].  Tile 64s x 64d per block.
__global__ __launch_bounds__(256) void vtrans_kernel(
    const __bf16* __restrict__ V, __bf16* __restrict__ Vt) {
  __shared__ __attribute__((aligned(16))) char T[64 * 144]; // row d, 144B stride
  const int bh = blockIdx.y, s0 = blockIdx.x * 64;
  const __bf16* Vb = V + (size_t)bh * S_ * HD_;
  __bf16* Vtb = Vt + (size_t)bh * HD_ * S_;
  const int tid = threadIdx.x;
#pragma unroll
  for (int j = 0; j < 2; ++j) {
    int c = tid + j * 256;            // s = c>>3, dc = c&7
    int s = c >> 3, dc = c & 7;
    bf16x8 v = *reinterpret_cast<const bf16x8*>(Vb + (size_t)(s0 + s) * HD_ + dc * 8);
#pragma unroll
    for (int e = 0; e < 8; ++e) {
      int d = dc * 8 + e;
      int byt = (d * 144 + s * 2) ^ ((dc & 7) << 4);   // spread banks by dc
      *reinterpret_cast<__bf16*>(T + byt) = v[e];
    }
  }
  __syncthreads();
#pragma unroll
  for (int j = 0; j < 2; ++j) {
    int c = tid + j * 256;            // d = c>>3, sc = c&7
    int d = c >> 3, sc = c & 7;
    int byt = (d * 144 + sc * 16) ^ (((d >> 3) & 7) << 4);
    bf16x8 o = *reinterpret_cast<const bf16x8*>(T + byt);
    *reinterpret_cast<bf16x8*>(Vtb + (size_t)d * S_ + s0 + sc * 8) = o;
  }
}

// Flash attention, causal. Grid: (bh=32, pr=16). Block: 4 waves x 16 q-rows,
// paired q-tiles (pr, 31-pr) => uniform 33 kv-iters per block.
// Swapped QK^T: sc = mfma(K_frag, Q_frag) -> D[key][q], q = lane&15.
// K staged with key-permutation kph so each lane's 16 P-values are exactly
// the PV B-fragment (k = (lane>>4)*8+i) -> softmax + P fully in registers.
__global__ __launch_bounds__(256) void attn_kernel(
    const __bf16* __restrict__ Q, const __bf16* __restrict__ K,
    const __bf16* __restrict__ Vt, __bf16* __restrict__ O) {
  __shared__ __attribute__((aligned(16))) __bf16 Ks[2][64 * 64];
  __shared__ __attribute__((aligned(16))) __bf16 Vs[2][64 * 64];
  const int tid = threadIdx.x, lane = tid & 63, wv = tid >> 6;
  const int bh = blockIdx.x;
  const int pr = blockIdx.y;
  const int b = bh >> 4, h = bh & 15;
  const __bf16* Qb  = Q  + (size_t)bh * S_ * HD_;
  const __bf16* Kb  = K  + (size_t)bh * S_ * HD_;
  const __bf16* Vtb = Vt + (size_t)bh * HD_ * S_;
  const int arow = lane & 15, g = lane >> 4;

#define STAGE(K0, BK_, BV_)                                                   \
  do {                                                                        \
    _Pragma("unroll") for (int j = 0; j < 2; ++j) {                           \
      int G = (wv * 2 + j) * 64 + lane;                                       \
      int row = G >> 3, qq = G & 7;                                           \
      int qs = qq ^ (row & 7);                                                \
      int ctp = row >> 4, rw = row & 15;                                      \
      int kph = ((ctp >> 1) << 5) + ((rw >> 2) << 3) + ((ctp & 1) << 2)       \
                + (rw & 3);                                                   \
      gload_lds16(Kb + (size_t)((K0) + kph) * HD_ + qs * 8,                   \
                  (BK_) + (wv * 2 + j) * 512);                                \
      gload_lds16(Vtb + (size_t)row * S_ + (K0) + qs * 8,                     \
                  (BV_) + (wv * 2 + j) * 512);                                \
    }                                                                         \
  } while (0)

  for (int seg = 0; seg < 2; ++seg) {
    const int qt = (seg == 0) ? pr : 31 - pr;
    const int q0 = qt * 64;
    const int nkv = qt + 1;
    const int qw = q0 + wv * 16;
    const int qg = qw + arow;          // this thread's q-row

    bf16x8 aq[2];
#pragma unroll
    for (int j = 0; j < 2; j++)
      aq[j] = *reinterpret_cast<const bf16x8*>(
          Qb + (size_t)(qw + arow) * HD_ + j * 32 + g * 8);

    f32x4 po[4];
#pragma unroll
    for (int dt = 0; dt < 4; dt++) po[dt] = f32x4{0.f, 0.f, 0.f, 0.f};
    float mrow = -1e30f, lrow = 0.f;

    STAGE(0, Ks[0], Vs[0]);
    asm volatile("s_waitcnt vmcnt(0)" ::: "memory");
    __syncthreads();

    for (int kt = 0; kt < nkv; ++kt) {
      const int k0 = kt * 64;
      const int cur = kt & 1;
      if (kt + 1 < nkv) STAGE(k0 + 64, Ks[cur ^ 1], Vs[cur ^ 1]);
      const __bf16* Kc = Ks[cur];
      const __bf16* Vc = Vs[cur];

      // S^T = K Q^T : D[key][q], 8 MFMA
      f32x4 sc4[4];
      __builtin_amdgcn_s_setprio(1);
#pragma unroll
      for (int ct = 0; ct < 4; ct++) {
        sc4[ct] = f32x4{0.f, 0.f, 0.f, 0.f};
        int L = ct * 16 + arow;
#pragma unroll
        for (int j2 = 0; j2 < 2; j2++) {
          int byt = (L * 128 + j2 * 64 + g * 16) ^ ((L & 7) << 4);
          bf16x8 kb = *reinterpret_cast<const bf16x8*>((const char*)Kc + byt);
          sc4[ct] = __builtin_amdgcn_mfma_f32_16x16x32_bf16(kb, aq[j2], sc4[ct], 0, 0, 0);
        }
      }
      __builtin_amdgcn_s_setprio(0);

      // causal mask (diagonal tile only)
      const bool full = (kt < nkv - 1);
      if (!full) {
#pragma unroll
        for (int ct = 0; ct < 4; ct++) {
          int kb0 = k0 + ((ct >> 1) << 5) + ((ct & 1) << 2) + g * 8;
#pragma unroll
          for (int r = 0; r < 4; r++)
            if (kb0 + r > qg) sc4[ct][r] = -1e30f;
        }
      }

      // in-register online softmax (one q-row per lane)
      float mx = -1e30f;
#pragma unroll
      for (int ct = 0; ct < 4; ct++)
#pragma unroll
        for (int r = 0; r < 4; r++) mx = fmaxf(mx, sc4[ct][r]);
      mx = fmaxf(mx, __shfl_xor(mx, 16, 64));
      mx = fmaxf(mx, __shfl_xor(mx, 32, 64));

      bool noskip = !__all(mx <= mrow + 11.0f);
      if (noskip) {
        float mnew = fmaxf(mrow, mx);
        float corr = fexp2(mrow - mnew);
        mrow = mnew;
        lrow *= corr;
#pragma unroll
        for (int dt = 0; dt < 4; dt++)
#pragma unroll
          for (int r = 0; r < 4; r++) po[dt][r] *= corr;
      }

      float rs = 0.f;
      float pv[4][4];
#pragma unroll
      for (int ct = 0; ct < 4; ct++)
#pragma unroll
        for (int r = 0; r < 4; r++) {
          float e = fexp2(sc4[ct][r] - mrow);
          pv[ct][r] = e;
          rs += e;
        }
      rs += __shfl_xor(rs, 16, 64);
      rs += __shfl_xor(rs, 32, 64);
      lrow += rs;

      // pack P: pb[j2] holds physical keys j2*32 + g*8 .. +7 (lane-local)
      bf16x8 pb[2];
#pragma unroll
      for (int j2 = 0; j2 < 2; j2++) {
#pragma unroll
        for (int r = 0; r < 4; r++) {
          pb[j2][r]     = (__bf16)pv[2 * j2][r];
          pb[j2][4 + r] = (__bf16)pv[2 * j2 + 1][r];
        }
      }

      // O^T += V^T P^T : po[dt] = D[d][q], d = dt*16 + g*4 + r, q = arow
      __builtin_amdgcn_s_setprio(1);
#pragma unroll
      for (int dt = 0; dt < 4; dt++) {
        int d = dt * 16 + arow;
#pragma unroll
        for (int j2 = 0; j2 < 2; j2++) {
          int byv = (d * 128 + j2 * 64 + g * 16) ^ ((d & 7) << 4);
          bf16x8 vb = *reinterpret_cast<const bf16x8*>((const char*)Vc + byv);
          po[dt] = __builtin_amdgcn_mfma_f32_16x16x32_bf16(vb, pb[j2], po[dt], 0, 0, 0);
        }
      }
      __builtin_amdgcn_s_setprio(0);

      asm volatile("s_waitcnt vmcnt(0)" ::: "memory");
      __syncthreads();
    }

    float inv = __builtin_amdgcn_rcpf(lrow);
#pragma unroll
    for (int dt = 0; dt < 4; dt++) {
      bf16x4 o4;
#pragma unroll
      for (int r = 0; r < 4; r++) o4[r] = (__bf16)(po[dt][r] * inv);
      *reinterpret_cast<bf16x4*>(
          O + (size_t)(b * S_ + qg) * D_ + h * HD_ + dt * 16 + g * 4) = o4;
    }
  }
#undef STAGE
}

extern "C" void kernel_launch(void* const* d_in, const int* in_sizes, int n_in,
                              void* d_out, int out_size, void* d_ws, size_t ws_size,
                              hipStream_t stream) {
  const float* x  = (const float*)d_in[0];
  const float* wq = (const float*)d_in[1];
  const float* wk = (const float*)d_in[2];
  const float* wv = (const float*)d_in[3];
  const float* wo = (const float*)d_in[4];
  float* out = (float*)d_out;

  char* w = (char*)d_ws;
  __bf16* xb  = (__bf16*)(w);                    // 8 MB (reused as Vt later)
  __bf16* wqb = (__bf16*)(w + (8u  << 20));      // 2 MB each
  __bf16* wkb = (__bf16*)(w + (10u << 20));
  __bf16* wvb = (__bf16*)(w + (12u << 20));
  __bf16* wob = (__bf16*)(w + (14u << 20));
  __bf16* qws = (__bf16*)(w + (16u << 20));      // 8 MB each, [B][H][S][hd]
  __bf16* kws = (__bf16*)(w + (24u << 20));
  __bf16* vws = (__bf16*)(w + (32u << 20));
  __bf16* aws = (__bf16*)(w + (40u << 20));      // attn out, [token][feature]
  float*  tab = (float*)(w + (48u << 20));       // 512 KB rope table
  __bf16* vtw = xb;                              // Vt overlays xb (dead after QKV)

  cvt_all_kernel<<<8448, 256, 0, stream>>>(x, wq, wk, wv, wo,
                                           xb, wqb, wkb, wvb, wob, tab);
  gemm_qkv8<<<dim3(16, 12), 512, 0, stream>>>(xb, wqb, wkb, wvb,
                                              qws, kws, vws, tab);
  vtrans_kernel<<<dim3(S_ / 64, 2 * H_), 256, 0, stream>>>(vws, vtw);
  attn_kernel<<<dim3(2 * H_, S_ / 128), 256, 0, stream>>>(qws, kws, vtw, aws);
  gemm_bt0<<<dim3(M_ / 128, D_ / 128), 256, 0, stream>>>(aws, wob, out,
                                                         M_, D_, D_);
}

// Round 6
// 142.096 us; speedup vs baseline: 1.1689x; 1.1170x over previous
//
#include <hip/hip_runtime.h>
#include <hip/hip_bf16.h>
#include <stdint.h>

typedef __attribute__((ext_vector_type(4))) float f32x4;
typedef __attribute__((ext_vector_type(8))) __bf16 bf16x8;
typedef __attribute__((ext_vector_type(4))) __bf16 bf16x4;

#define DEVI __device__ __forceinline__

static constexpr int S_  = 2048;
static constexpr int D_  = 1024;
static constexpr int H_  = 16;
static constexpr int HD_ = 64;
static constexpr int M_  = 2 * S_;   // B*S = 4096 token rows
static constexpr float SCL2 = 0.18033688f;  // 0.125 * log2(e)

DEVI void gload_lds16(const void* gsrc, void* ldst) {
  __builtin_amdgcn_global_load_lds(
      (__attribute__((address_space(1))) void*)(void*)gsrc,
      (__attribute__((address_space(3))) void*)ldst, 16, 0, 0);
}

DEVI float fexp2(float x) {
  float r;
  asm("v_exp_f32 %0, %1" : "=v"(r) : "v"(x));
  return r;
}

// One fused conversion kernel: x + 4 weights fp32->bf16, plus RoPE table.
__global__ __launch_bounds__(256) void cvt_all_kernel(
    const float* __restrict__ x, const float* __restrict__ wq,
    const float* __restrict__ wk, const float* __restrict__ wv,
    const float* __restrict__ wo,
    __bf16* __restrict__ xb, __bf16* __restrict__ wqb,
    __bf16* __restrict__ wkb, __bf16* __restrict__ wvb,
    __bf16* __restrict__ wob, float* __restrict__ tab) {
  int blk = blockIdx.x;
  if (blk < 8192) {
    int i = blk * 256 + threadIdx.x;     // float4 index
    const float* src; __bf16* dst; int off;
    if (i < (1 << 20))                      { src = x;  dst = xb;  off = 0; }
    else if (i < (1 << 20) + (1 << 18))     { src = wq; dst = wqb; off = (1 << 20); }
    else if (i < (1 << 20) + 2 * (1 << 18)) { src = wk; dst = wkb; off = (1 << 20) + (1 << 18); }
    else if (i < (1 << 20) + 3 * (1 << 18)) { src = wv; dst = wvb; off = (1 << 20) + 2 * (1 << 18); }
    else                                    { src = wo; dst = wob; off = (1 << 20) + 3 * (1 << 18); }
    int j = i - off;
    float4 v = reinterpret_cast<const float4*>(src)[j];
    bf16x4 o;
    o[0] = (__bf16)v.x; o[1] = (__bf16)v.y; o[2] = (__bf16)v.z; o[3] = (__bf16)v.w;
    reinterpret_cast<bf16x4*>(dst)[j] = o;
  } else {
    int i = (blk - 8192) * 256 + threadIdx.x;   // 0..65535 = S*32
    int s = i >> 5, f = i & 31;
    float freq = powf(10000.0f, -(float)(2 * f) / (float)HD_);
    float ang = (float)s * freq;
    tab[2 * i]     = cosf(ang);
    tab[2 * i + 1] = sinf(ang);
  }
}

// ---------------------------------------------------------------------------
// QKV GEMM: m97 128x128 structure (proven, round-3) with BK=64 (half the
// barrier/vmcnt events) + XOR swizzle (byte ^= (row&7)<<4) applied via
// pre-swizzled global source (linear global_load_lds dest) + swizzled read
// -- without it BK=64's 128B row stride is a 16-way bank conflict.
// grid (32, 8, 3): z selects Q/K/V weight; epilogue fuses RoPE + head-split.
// ---------------------------------------------------------------------------
__global__ __launch_bounds__(256) void gemm_qkv(
    const __bf16* __restrict__ A, const __bf16* __restrict__ W0,
    const __bf16* __restrict__ W1, const __bf16* __restrict__ W2,
    __bf16* __restrict__ Cq, __bf16* __restrict__ Ck, __bf16* __restrict__ Cv,
    const float* __restrict__ tab) {
  __shared__ __attribute__((aligned(16))) char As[128 * 128];  // 128 rows x 128B
  __shared__ __attribute__((aligned(16))) char Bs[128 * 128];
  const int tid  = threadIdx.x;
  const int lane = tid & 63;
  const int wv   = tid >> 6;
  const int m0 = blockIdx.x * 128;
  const int n0 = blockIdx.y * 128;
  const int z  = blockIdx.z;
  const __bf16* W = (z == 0) ? W0 : (z == 1 ? W1 : W2);
  const __bf16* Ab = A + (size_t)m0 * 1024;
  const __bf16* Wb = W + (size_t)n0 * 1024;
  const int wm = (wv >> 1) * 64, wn = (wv & 1) * 64;
  const int arow = lane & 15;
  const int g16  = (lane >> 4) * 16;   // byte offset of k-group within row

  f32x4 acc[4][4];
#pragma unroll
  for (int i = 0; i < 4; i++)
#pragma unroll
    for (int j = 0; j < 4; j++) acc[i][j] = f32x4{0.f, 0.f, 0.f, 0.f};

  for (int k0 = 0; k0 < 1024; k0 += 64) {
    __syncthreads();   // previous iteration's LDS reads done
#pragma unroll
    for (int j = 0; j < 4; ++j) {
      int c   = (wv * 4 + j) * 64 + lane;   // 16B chunk id 0..1023
      int row = c >> 3;
      int qq  = c & 7;
      int qs  = qq ^ (row & 7);             // inverse swizzle on source
      gload_lds16(Ab + (size_t)row * 1024 + k0 + qs * 8,
                  As + (wv * 4 + j) * 1024);
      gload_lds16(Wb + (size_t)row * 1024 + k0 + qs * 8,
                  Bs + (wv * 4 + j) * 1024);
    }
    asm volatile("s_waitcnt vmcnt(0)" ::: "memory");
    __syncthreads();
#pragma unroll
    for (int ks = 0; ks < 2; ++ks) {
      bf16x8 af[4], bw[4];
#pragma unroll
      for (int i = 0; i < 4; i++) {
        int r = wm + i * 16 + arow;
        int byt = (r * 128 + ks * 64 + g16) ^ ((r & 7) << 4);
        af[i] = *reinterpret_cast<const bf16x8*>(As + byt);
      }
#pragma unroll
      for (int i = 0; i < 4; i++) {
        int r = wn + i * 16 + arow;
        int byt = (r * 128 + ks * 64 + g16) ^ ((r & 7) << 4);
        bw[i] = *reinterpret_cast<const bf16x8*>(Bs + byt);
      }
#pragma unroll
      for (int i = 0; i < 4; i++)
#pragma unroll
        for (int j = 0; j < 4; j++)
          acc[i][j] = __builtin_amdgcn_mfma_f32_16x16x32_bf16(af[i], bw[j], acc[i][j], 0, 0, 0);
    }
  }

  // epilogue: RoPE + head-split. C/D: col=lane&15 (n), row=(lane>>4)*4+r (m)
#pragma unroll
  for (int i = 0; i < 4; i++) {
#pragma unroll
    for (int j = 0; j < 4; j++) {
#pragma unroll
      for (int r = 0; r < 4; r++) {
        int m = m0 + wm + i * 16 + (lane >> 4) * 4 + r;
        int n = n0 + wn + j * 16 + arow;
        float v = acc[i][j][r];
        int bb = m >> 11, srow = m & (S_ - 1);
        int h = n >> 6, d = n & 63;
        size_t oidx = ((size_t)(bb * H_ + h) * S_ + srow) * HD_ + d;
        float other = __shfl_xor(v, 1, 64);   // n bit0 == lane bit0
        if (z == 2) {
          Cv[oidx] = (__bf16)v;
        } else {
          int fq = d >> 1;
          float2 cssn = *reinterpret_cast<const float2*>(tab + (srow * 32 + fq) * 2);
          float rv = (d & 1) ? (other * cssn.y + v * cssn.x)
                             : (v * cssn.x - other * cssn.y);
          if (z == 0) rv *= SCL2;   // pre-scale Q: logits in exp2 domain
          ((z == 0) ? Cq : Ck)[oidx] = (__bf16)rv;
        }
      }
    }
  }
}

// O-projection: C[m][n] = sum_k A[m][k] * W[n][k], fp32 out (m97, BK=32 control)
__global__ __launch_bounds__(256) void gemm_bt0(
    const __bf16* __restrict__ A, const __bf16* __restrict__ W0,
    float* __restrict__ Cf, int M, int N, int K) {
  constexpr int BM = 128, BN = 128, BK = 32;
  __shared__ __attribute__((aligned(16))) __bf16 As[BM * BK];
  __shared__ __attribute__((aligned(16))) __bf16 Bs[BN * BK];
  const int tid  = threadIdx.x;
  const int lane = tid & 63;
  const int wv   = tid >> 6;
  const int m0 = blockIdx.x * BM;
  const int n0 = blockIdx.y * BN;
  const int wm = (wv >> 1) * 64, wn = (wv & 1) * 64;
  const int arow = lane & 15;
  const int kgrp = (lane >> 4) * 8;

  f32x4 acc[4][4];
#pragma unroll
  for (int i = 0; i < 4; i++)
#pragma unroll
    for (int j = 0; j < 4; j++) acc[i][j] = f32x4{0.f, 0.f, 0.f, 0.f};

  for (int k0 = 0; k0 < K; k0 += BK) {
    __syncthreads();
#pragma unroll
    for (int j = 0; j < 2; ++j) {
      int c   = (wv * 2 + j) * 64 + lane;
      int row = c >> 2;
      int kc  = (c & 3) * 8;
      gload_lds16(A + (size_t)(m0 + row) * K + k0 + kc,
                  As + (size_t)(wv * 2 + j) * 512);
      gload_lds16(W0 + (size_t)(n0 + row) * K + k0 + kc,
                  Bs + (size_t)(wv * 2 + j) * 512);
    }
    asm volatile("s_waitcnt vmcnt(0)" ::: "memory");
    __syncthreads();
    bf16x8 af[4], bw[4];
#pragma unroll
    for (int i = 0; i < 4; i++)
      af[i] = *reinterpret_cast<const bf16x8*>(As + (wm + i * 16 + arow) * BK + kgrp);
#pragma unroll
    for (int i = 0; i < 4; i++)
      bw[i] = *reinterpret_cast<const bf16x8*>(Bs + (wn + i * 16 + arow) * BK + kgrp);
#pragma unroll
    for (int i = 0; i < 4; i++)
#pragma unroll
      for (int j = 0; j < 4; j++)
        acc[i][j] = __builtin_amdgcn_mfma_f32_16x16x32_bf16(af[i], bw[j], acc[i][j], 0, 0, 0);
  }

#pragma unroll
  for (int i = 0; i < 4; i++)
#pragma unroll
    for (int j = 0; j < 4; j++)
#pragma unroll
      for (int r = 0; r < 4; r++) {
        int m = m0 + wm + i * 16 + (lane >> 4) * 4 + r;
        int n = n0 + wn + j * 16 + arow;
        Cf[(size_t)m * N + n] = acc[i][j][r];
      }
}

// V [bh][s][d=64] -> Vt [bh][d][s].  Tile 64s x 64d per block.
__global__ __launch_bounds__(256) void vtrans_kernel(
    const __bf16* __restrict__ V, __bf16* __restrict__ Vt) {
  __shared__ __attribute__((aligned(16))) char T[64 * 144]; // row d, 144B stride
  const int bh = blockIdx.y, s0 = blockIdx.x * 64;
  const __bf16* Vb = V + (size_t)bh * S_ * HD_;
  __bf16* Vtb = Vt + (size_t)bh * HD_ * S_;
  const int tid = threadIdx.x;
#pragma unroll
  for (int j = 0; j < 2; ++j) {
    int c = tid + j * 256;            // s = c>>3, dc = c&7
    int s = c >> 3, dc = c & 7;
    bf16x8 v = *reinterpret_cast<const bf16x8*>(Vb + (size_t)(s0 + s) * HD_ + dc * 8);
#pragma unroll
    for (int e = 0; e < 8; ++e) {
      int d = dc * 8 + e;
      int byt = (d * 144 + s * 2) ^ ((dc & 7) << 4);   // spread banks by dc
      *reinterpret_cast<__bf16*>(T + byt) = v[e];
    }
  }
  __syncthreads();
#pragma unroll
  for (int j = 0; j < 2; ++j) {
    int c = tid + j * 256;            // d = c>>3, sc = c&7
    int d = c >> 3, sc = c & 7;
    int byt = (d * 144 + sc * 16) ^ (((d >> 3) & 7) << 4);
    bf16x8 o = *reinterpret_cast<const bf16x8*>(T + byt);
    *reinterpret_cast<bf16x8*>(Vtb + (size_t)d * S_ + s0 + sc * 8) = o;
  }
}

// Flash attention, causal. Grid: (bh=32, pr=16). Block: 4 waves x 16 q-rows,
// paired q-tiles (pr, 31-pr) => uniform 33 kv-iters per block.
// Swapped QK^T (P lane-local) + counted-vmcnt staging pipeline:
// per iter: compute -> barrier -> STAGE(kt+2, clamped; uniform 4 loads)
// -> vmcnt(4) [waits only tile kt+1, issued a full iter ago] -> barrier.
// Last iter drains vmcnt(0) to protect the next segment's prologue.
__global__ __launch_bounds__(256) void attn_kernel(
    const __bf16* __restrict__ Q, const __bf16* __restrict__ K,
    const __bf16* __restrict__ Vt, __bf16* __restrict__ O) {
  __shared__ __attribute__((aligned(16))) __bf16 Ks[2][64 * 64];
  __shared__ __attribute__((aligned(16))) __bf16 Vs[2][64 * 64];
  const int tid = threadIdx.x, lane = tid & 63, wv = tid >> 6;
  const int bh = blockIdx.x;   // stride-32 linear ids: all pr of one bh share an XCD
  const int pr = blockIdx.y;
  const int b = bh >> 4, h = bh & 15;
  const __bf16* Qb  = Q  + (size_t)bh * S_ * HD_;
  const __bf16* Kb  = K  + (size_t)bh * S_ * HD_;
  const __bf16* Vtb = Vt + (size_t)bh * HD_ * S_;
  const int arow = lane & 15, g = lane >> 4;

#define STAGE(K0, BK_, BV_)                                                   \
  do {                                                                        \
    _Pragma("unroll") for (int j = 0; j < 2; ++j) {                           \
      int G = (wv * 2 + j) * 64 + lane;                                       \
      int row = G >> 3, qq = G & 7;                                           \
      int qs = qq ^ (row & 7);                                                \
      int ctp = row >> 4, rw = row & 15;                                      \
      int kph = ((ctp >> 1) << 5) + ((rw >> 2) << 3) + ((ctp & 1) << 2)       \
                + (rw & 3);                                                   \
      gload_lds16(Kb + (size_t)((K0) + kph) * HD_ + qs * 8,                   \
                  (BK_) + (wv * 2 + j) * 512);                                \
      gload_lds16(Vtb + (size_t)row * S_ + (K0) + qs * 8,                     \
                  (BV_) + (wv * 2 + j) * 512);                                \
    }                                                                         \
  } while (0)

  for (int seg = 0; seg < 2; ++seg) {
    const int qt = (seg == 0) ? pr : 31 - pr;
    const int q0 = qt * 64;
    const int nkv = qt + 1;
    const int qw = q0 + wv * 16;
    const int qg = qw + arow;          // this thread's q-row

    bf16x8 aq[2];
#pragma unroll
    for (int j = 0; j < 2; j++)
      aq[j] = *reinterpret_cast<const bf16x8*>(
          Qb + (size_t)(qw + arow) * HD_ + j * 32 + g * 8);

    f32x4 po[4];
#pragma unroll
    for (int dt = 0; dt < 4; dt++) po[dt] = f32x4{0.f, 0.f, 0.f, 0.f};
    float mrow = -1e30f, lrow = 0.f;

    // prologue: stage tiles 0 and 1 (clamped); vmcnt(4) -> tile 0 landed
    STAGE(0, Ks[0], Vs[0]);
    {
      int t1 = (nkv > 1) ? 64 : 0;
      STAGE(t1, Ks[1], Vs[1]);
    }
    asm volatile("s_waitcnt vmcnt(4)" ::: "memory");
    __builtin_amdgcn_s_barrier();

    for (int kt = 0; kt < nkv; ++kt) {
      const int k0 = kt * 64;
      const int cur = kt & 1;
      const __bf16* Kc = Ks[cur];
      const __bf16* Vc = Vs[cur];

      // S^T = K Q^T : D[key][q], 8 MFMA
      f32x4 sc4[4];
      __builtin_amdgcn_s_setprio(1);
#pragma unroll
      for (int ct = 0; ct < 4; ct++) {
        sc4[ct] = f32x4{0.f, 0.f, 0.f, 0.f};
        int L = ct * 16 + arow;
#pragma unroll
        for (int j2 = 0; j2 < 2; j2++) {
          int byt = (L * 128 + j2 * 64 + g * 16) ^ ((L & 7) << 4);
          bf16x8 kb = *reinterpret_cast<const bf16x8*>((const char*)Kc + byt);
          sc4[ct] = __builtin_amdgcn_mfma_f32_16x16x32_bf16(kb, aq[j2], sc4[ct], 0, 0, 0);
        }
      }
      __builtin_amdgcn_s_setprio(0);

      // causal mask (diagonal tile only)
      const bool full = (kt < nkv - 1);
      if (!full) {
#pragma unroll
        for (int ct = 0; ct < 4; ct++) {
          int kb0 = k0 + ((ct >> 1) << 5) + ((ct & 1) << 2) + g * 8;
#pragma unroll
          for (int r = 0; r < 4; r++)
            if (kb0 + r > qg) sc4[ct][r] = -1e30f;
        }
      }

      // in-register online softmax (one q-row per lane)
      float mx = -1e30f;
#pragma unroll
      for (int ct = 0; ct < 4; ct++)
#pragma unroll
        for (int r = 0; r < 4; r++) mx = fmaxf(mx, sc4[ct][r]);
      mx = fmaxf(mx, __shfl_xor(mx, 16, 64));
      mx = fmaxf(mx, __shfl_xor(mx, 32, 64));

      bool noskip = !__all(mx <= mrow + 11.0f);
      if (noskip) {
        float mnew = fmaxf(mrow, mx);
        float corr = fexp2(mrow - mnew);
        mrow = mnew;
        lrow *= corr;
#pragma unroll
        for (int dt = 0; dt < 4; dt++)
#pragma unroll
          for (int r = 0; r < 4; r++) po[dt][r] *= corr;
      }

      float rs = 0.f;
      float pv[4][4];
#pragma unroll
      for (int ct = 0; ct < 4; ct++)
#pragma unroll
        for (int r = 0; r < 4; r++) {
          float e = fexp2(sc4[ct][r] - mrow);
          pv[ct][r] = e;
          rs += e;
        }
      rs += __shfl_xor(rs, 16, 64);
      rs += __shfl_xor(rs, 32, 64);
      lrow += rs;

      // pack P: pb[j2] holds physical keys j2*32 + g*8 .. +7 (lane-local)
      bf16x8 pb[2];
#pragma unroll
      for (int j2 = 0; j2 < 2; j2++) {
#pragma unroll
        for (int r = 0; r < 4; r++) {
          pb[j2][r]     = (__bf16)pv[2 * j2][r];
          pb[j2][4 + r] = (__bf16)pv[2 * j2 + 1][r];
        }
      }

      // O^T += V^T P^T : po[dt] = D[d][q], d = dt*16 + g*4 + r, q = arow
      __builtin_amdgcn_s_setprio(1);
#pragma unroll
      for (int dt = 0; dt < 4; dt++) {
        int d = dt * 16 + arow;
#pragma unroll
        for (int j2 = 0; j2 < 2; j2++) {
          int byv = (d * 128 + j2 * 64 + g * 16) ^ ((d & 7) << 4);
          bf16x8 vb = *reinterpret_cast<const bf16x8*>((const char*)Vc + byv);
          po[dt] = __builtin_amdgcn_mfma_f32_16x16x32_bf16(vb, pb[j2], po[dt], 0, 0, 0);
        }
      }
      __builtin_amdgcn_s_setprio(0);

      // pipeline tail: all waves done reading buf[cur], then stage kt+2
      __builtin_amdgcn_s_barrier();
      if (kt < nkv - 1) {
        int nx = kt + 2;
        if (nx > nkv - 1) nx = nkv - 1;     // clamp: uniform 4-load count
        STAGE(nx * 64, Ks[cur], Vs[cur]);   // overwrite retired buffer
        asm volatile("s_waitcnt vmcnt(4)" ::: "memory");  // tile kt+1 landed
      } else {
        asm volatile("s_waitcnt vmcnt(0)" ::: "memory");  // drain for next seg
      }
      __builtin_amdgcn_s_barrier();
    }

    float inv = __builtin_amdgcn_rcpf(lrow);
#pragma unroll
    for (int dt = 0; dt < 4; dt++) {
      bf16x4 o4;
#pragma unroll
      for (int r = 0; r < 4; r++) o4[r] = (__bf16)(po[dt][r] * inv);
      *reinterpret_cast<bf16x4*>(
          O + (size_t)(b * S_ + qg) * D_ + h * HD_ + dt * 16 + g * 4) = o4;
    }
  }
#undef STAGE
}

extern "C" void kernel_launch(void* const* d_in, const int* in_sizes, int n_in,
                              void* d_out, int out_size, void* d_ws, size_t ws_size,
                              hipStream_t stream) {
  const float* x  = (const float*)d_in[0];
  const float* wq = (const float*)d_in[1];
  const float* wk = (const float*)d_in[2];
  const float* wv = (const float*)d_in[3];
  const float* wo = (const float*)d_in[4];
  float* out = (float*)d_out;

  char* w = (char*)d_ws;
  __bf16* xb  = (__bf16*)(w);                    // 8 MB (reused as Vt later)
  __bf16* wqb = (__bf16*)(w + (8u  << 20));      // 2 MB each
  __bf16* wkb = (__bf16*)(w + (10u << 20));
  __bf16* wvb = (__bf16*)(w + (12u << 20));
  __bf16* wob = (__bf16*)(w + (14u << 20));
  __bf16* qws = (__bf16*)(w + (16u << 20));      // 8 MB each, [B][H][S][hd]
  __bf16* kws = (__bf16*)(w + (24u << 20));
  __bf16* vws = (__bf16*)(w + (32u << 20));
  __bf16* aws = (__bf16*)(w + (40u << 20));      // attn out, [token][feature]
  float*  tab = (float*)(w + (48u << 20));       // 512 KB rope table
  __bf16* vtw = xb;                              // Vt overlays xb (dead after QKV)

  cvt_all_kernel<<<8448, 256, 0, stream>>>(x, wq, wk, wv, wo,
                                           xb, wqb, wkb, wvb, wob, tab);
  gemm_qkv<<<dim3(32, 8, 3), 256, 0, stream>>>(xb, wqb, wkb, wvb,
                                               qws, kws, vws, tab);
  vtrans_kernel<<<dim3(S_ / 64, 2 * H_), 256, 0, stream>>>(vws, vtw);
  attn_kernel<<<dim3(2 * H_, S_ / 128), 256, 0, stream>>>(qws, kws, vtw, aws);
  gemm_bt0<<<dim3(M_ / 128, D_ / 128), 256, 0, stream>>>(aws, wob, out,
                                                         M_, D_, D_);
}